// Round 2
// baseline (847.370 us; speedup 1.0000x reference)
//
#include <hip/hip_runtime.h>
#include <hip/hip_fp16.h>
#include <cstdint>
#include <cstddef>

#define NN 100000
#define NE 800000
#define DIM 64
#define HEADS 4
#define HEAD_DIM 16
#define ALPHA 0.1f
#define K_ITERS 8
#define NBLK 391  // ceil(NN/256)

typedef short bf16x8 __attribute__((ext_vector_type(8)));
typedef float f32x4 __attribute__((ext_vector_type(4)));
typedef float fvec4 __attribute__((ext_vector_type(4)));  // for nontemporal builtin

__device__ __forceinline__ unsigned short f2bf(float f) {
    unsigned int x = __float_as_uint(f);
    unsigned int r = (x + 0x7fffu + ((x >> 16) & 1u)) >> 16;  // RNE
    return (unsigned short)r;
}
__device__ __forceinline__ float bf_lo(unsigned int p) { return __uint_as_float(p << 16); }
__device__ __forceinline__ float bf_hi(unsigned int p) { return __uint_as_float(p & 0xffff0000u); }

__device__ __forceinline__ float2 h2f(unsigned int v) {
    __half2 h = *(__half2*)&v;
    return __half22float2(h);
}
__device__ __forceinline__ unsigned int f2h2(float a, float b) {
    __half2 h = __floats2half2_rn(a, b);
    return *(unsigned int*)&h;
}
__device__ __forceinline__ float dot8h(uint4 a, uint4 b) {
    float2 a0 = h2f(a.x), b0 = h2f(b.x);
    float2 a1 = h2f(a.y), b1 = h2f(b.y);
    float2 a2 = h2f(a.z), b2 = h2f(b.z);
    float2 a3 = h2f(a.w), b3 = h2f(b.w);
    return a0.x * b0.x + a0.y * b0.y + a1.x * b1.x + a1.y * b1.y
         + a2.x * b2.x + a2.y * b2.y + a3.x * b3.x + a3.y * b3.y;
}

// NOTE: macro parameter must NOT be named 'z' (or x/y/w) — member tokens
// .x/.y/.z/.w would be substituted too.
#define ACC8(a, V) { float2 t_; \
    t_ = h2f((V).x); m[0] += (a) * t_.x; m[1] += (a) * t_.y; \
    t_ = h2f((V).y); m[2] += (a) * t_.x; m[3] += (a) * t_.y; \
    t_ = h2f((V).z); m[4] += (a) * t_.x; m[5] += (a) * t_.y; \
    t_ = h2f((V).w); m[6] += (a) * t_.x; m[7] += (a) * t_.y; }

// att extractor from packed rec: rec.y holds heads 0,1; rec.z holds heads 2,3.
__device__ __forceinline__ float rec_att(uint4 r, int head) {
    unsigned int pair = (head & 2) ? r.z : r.y;
    float2 f = h2f(pair);
    return (head & 1) ? f.y : f.x;
}

// MFMA qkv+u: block = 64 nodes, 4 waves x 16 rows each. (unchanged)
__global__ __launch_bounds__(256) void qkv_mfma_kernel(
    const float* __restrict__ x,
    const float* __restrict__ Wq, const float* __restrict__ Wk,
    const float* __restrict__ Wv, const float* __restrict__ We,
    __half* __restrict__ qh, __half* __restrict__ kh, __half* __restrict__ vh,
    unsigned short* __restrict__ u)
{
    __shared__ unsigned short sq[64 * 72];
    int tid = threadIdx.x;
    int w = tid >> 6;
    int lane = tid & 63;
    int m16 = lane & 15;
    int quad = lane >> 4;
    int node = blockIdx.x * 64 + w * 16 + m16;
    int nodeC = node < NN ? node : NN - 1;

    bf16x8 afrag[2];
    #pragma unroll
    for (int kk = 0; kk < 2; ++kk) {
        const float* xr = x + (size_t)nodeC * DIM + kk * 32 + quad * 8;
        #pragma unroll
        for (int j = 0; j < 8; ++j) afrag[kk][j] = (short)f2bf(xr[j]);
    }

    const float* Ws[3] = {Wq, Wk, Wv};
    __half* outs[3] = {qh, kh, vh};

    #pragma unroll
    for (int mtx = 0; mtx < 3; ++mtx) {
        const float* W = Ws[mtx];
        #pragma unroll
        for (int n0 = 0; n0 < 64; n0 += 16) {
            int col = n0 + m16;
            f32x4 acc = {0.f, 0.f, 0.f, 0.f};
            #pragma unroll
            for (int kk = 0; kk < 2; ++kk) {
                bf16x8 bfrag;
                #pragma unroll
                for (int j = 0; j < 8; ++j)
                    bfrag[j] = (short)f2bf(W[(kk * 32 + quad * 8 + j) * DIM + col]);
                acc = __builtin_amdgcn_mfma_f32_16x16x32_bf16(afrag[kk], bfrag, acc, 0, 0, 0);
            }
            if (mtx == 0) {
                #pragma unroll
                for (int r = 0; r < 4; ++r) acc[r] *= 0.25f;  // fold 1/sqrt(HEAD_DIM)
            }
            #pragma unroll
            for (int r = 0; r < 4; ++r) {
                int rl = w * 16 + quad * 4 + r;
                int gnode = blockIdx.x * 64 + rl;
                if (mtx == 0) sq[rl * 72 + col] = f2bf(acc[r]);
                if (gnode < NN) outs[mtx][(size_t)gnode * DIM + col] = __float2half(acc[r]);
            }
        }
    }
    __syncthreads();

    #pragma unroll
    for (int h = 0; h < HEADS; ++h) {
        int kk = h >> 1;
        bf16x8 aq;
        const unsigned short* sr = &sq[(w * 16 + m16) * 72 + kk * 32 + quad * 8];
        #pragma unroll
        for (int j = 0; j < 8; ++j) aq[j] = (short)sr[j];
        #pragma unroll
        for (int c0 = 0; c0 < 64; c0 += 16) {
            int c = c0 + m16;
            bf16x8 bfrag;
            #pragma unroll
            for (int j = 0; j < 8; ++j) {
                int k = kk * 32 + quad * 8 + j;
                bfrag[j] = ((k >> 4) == h) ? (short)f2bf(We[c * DIM + k]) : (short)0;
            }
            f32x4 acc = {0.f, 0.f, 0.f, 0.f};
            acc = __builtin_amdgcn_mfma_f32_16x16x32_bf16(aq, bfrag, acc, 0, 0, 0);
            #pragma unroll
            for (int r = 0; r < 4; ++r) {
                int gnode = blockIdx.x * 64 + w * 16 + quad * 4 + r;
                if (gnode < NN) u[(size_t)gnode * 256 + h * 64 + c] = f2bf(acc[r]);
            }
        }
    }
}

__global__ void init_kernel(int* __restrict__ deg) {
    int i = blockIdx.x * 256 + threadIdx.x;
    if (i < NN) deg[i] = 0;
}

__global__ void deg_kernel(const int* __restrict__ ei, int* __restrict__ deg) {
    int e = blockIdx.x * 256 + threadIdx.x;
    if (e >= NE) return;
    atomicAdd(&deg[ei[NE + e]], 1);
}

__global__ void blocksum_kernel(const int* __restrict__ deg, int* __restrict__ bsum) {
    int t = threadIdx.x, b = blockIdx.x;
    int idx = b * 256 + t;
    int v = (idx < NN) ? deg[idx] : 0;
    #pragma unroll
    for (int off = 32; off > 0; off >>= 1) v += __shfl_down(v, off);
    __shared__ int wsum[4];
    if ((t & 63) == 0) wsum[t >> 6] = v;
    __syncthreads();
    if (t == 0) bsum[b] = wsum[0] + wsum[1] + wsum[2] + wsum[3];
}

__global__ void bscan_kernel(const int* __restrict__ bsum, int* __restrict__ boff) {
    __shared__ int s[512];
    int t = threadIdx.x;
    int v = (t < NBLK) ? bsum[t] : 0;
    s[t] = v;
    __syncthreads();
    for (int off = 1; off < 512; off <<= 1) {
        int u = (t >= off) ? s[t - off] : 0;
        __syncthreads();
        s[t] += u;
        __syncthreads();
    }
    if (t < NBLK) boff[t] = s[t] - v;
}

__global__ void rowptr_kernel(const int* __restrict__ deg, const int* __restrict__ boff,
                              int* __restrict__ row_ptr, int* __restrict__ cursor) {
    __shared__ int s[256];
    int t = threadIdx.x, b = blockIdx.x;
    int idx = b * 256 + t;
    int v = (idx < NN) ? deg[idx] : 0;
    s[t] = v;
    __syncthreads();
    for (int off = 1; off < 256; off <<= 1) {
        int u = (t >= off) ? s[t - off] : 0;
        __syncthreads();
        s[t] += u;
        __syncthreads();
    }
    if (idx < NN) {
        int ex = boff[b] + s[t] - v;
        row_ptr[idx] = ex;
        cursor[idx] = ex;
    }
    if (idx == 0) row_ptr[NN] = NE;
}

__global__ void scatter_kernel(const int* __restrict__ ei,
                               int* __restrict__ cursor,
                               int* __restrict__ csr_src,
                               int* __restrict__ csr_e,
                               int* __restrict__ csr_dst) {
    int e = blockIdx.x * 256 + threadIdx.x;
    if (e >= NE) return;
    int src = ei[e], dst = ei[NE + e];
    int pos = atomicAdd(&cursor[dst], 1);
    csr_src[pos] = src;
    csr_e[pos] = e;
    csr_dst[pos] = dst;
}

// Edge-ORDER logits: edge_attr is a fully-coalesced 205 MB stream (nontemporal,
// read-once); u/qh/kh become random gathers against L3-resident arrays.
// No atomics. att_e written coalesced in edge order (raw exp, fp16).
__global__ __launch_bounds__(256) void logits_edge_kernel(
    const __half* __restrict__ qh,
    const __half* __restrict__ kh,
    const float* __restrict__ edge_attr,
    const unsigned short* __restrict__ u,
    const int* __restrict__ ei,
    __half* __restrict__ att_e) {
    int idx = blockIdx.x * 256 + threadIdx.x;
    if (idx >= NE * HEADS) return;
    int e = idx >> 2, h = idx & 3;
    int src = ei[e], dst = ei[NE + e];
    const fvec4* attr4 = (const fvec4*)edge_attr + (size_t)e * 16;
    const uint4* u4 = (const uint4*)u + (size_t)dst * 32 + h * 8;
    float au = 0.f;
    #pragma unroll
    for (int i = 0; i < 8; ++i) {
        uint4 up = u4[i];
        fvec4 a0 = __builtin_nontemporal_load(attr4 + 2 * i);
        fvec4 a1 = __builtin_nontemporal_load(attr4 + 2 * i + 1);
        au += a0.x * bf_lo(up.x) + a0.y * bf_hi(up.x)
            + a0.z * bf_lo(up.y) + a0.w * bf_hi(up.y)
            + a1.x * bf_lo(up.z) + a1.y * bf_hi(up.z)
            + a1.z * bf_lo(up.w) + a1.w * bf_hi(up.w);
    }
    const uint4* qq = (const uint4*)qh + (size_t)dst * 8 + h * 2;
    const uint4* kk = (const uint4*)kh + (size_t)src * 8 + h * 2;
    float qk = dot8h(qq[0], kk[0]) + dot8h(qq[1], kk[1]);
    float ex = __expf(qk + au);  // logits bounded ~8; exp safe (shift-invariant)
    att_e[idx] = __float2half(ex);
}

// Segmented denom (replaces atomics): one thread per (node,head), CSR walk,
// gather raw exps via csr_e. rinv = 0.9/denom folded once.
__global__ void rinv_kernel(const __half* __restrict__ att_e,
                            const int* __restrict__ csr_e,
                            const int* __restrict__ row_ptr,
                            float* __restrict__ rinv) {
    int idx = blockIdx.x * 256 + threadIdx.x;
    if (idx >= NN * HEADS) return;
    int n = idx >> 2, h = idx & 3;
    int beg = row_ptr[n], end = row_ptr[n + 1];
    float s = 0.f;
    int j = beg;
    for (; j + 2 <= end; j += 2) {
        int e0 = csr_e[j], e1 = csr_e[j + 1];
        float a0 = __half2float(att_e[e0 * 4 + h]);
        float a1 = __half2float(att_e[e1 * 4 + h]);
        s += a0 + a1;
    }
    if (j < end) s += __half2float(att_e[csr_e[j] * 4 + h]);
    rinv[idx] = 0.9f / (s + 1e-16f);
}

// Pack per-CSR-slot record: {src, fp16 att*rinv for 4 heads, pad}.
// Prop then needs exactly ONE uniform 16B load + one z gather per edge.
__global__ void recs_kernel(const __half* __restrict__ att_e,
                            const int* __restrict__ csr_src,
                            const int* __restrict__ csr_e,
                            const int* __restrict__ csr_dst,
                            const float* __restrict__ rinv,
                            uint4* __restrict__ recs) {
    int j = blockIdx.x * 256 + threadIdx.x;
    if (j >= NE) return;
    int e = csr_e[j], src = csr_src[j], dst = csr_dst[j];
    uint2 ap = *(const uint2*)(att_e + (size_t)e * 4);
    float2 e01 = h2f(ap.x), e23 = h2f(ap.y);
    float4 rv = *(const float4*)(rinv + (size_t)dst * 4);
    uint4 rec;
    rec.x = (unsigned int)src;
    rec.y = f2h2(e01.x * rv.x, e01.y * rv.y);
    rec.z = f2h2(e23.x * rv.z, e23.y * rv.w);
    rec.w = 0u;
    recs[j] = rec;
}

// Propagation: 8 lanes/node, 8 dims/lane. Weights pre-normalized (x0.9/denom),
// so z_out = alpha*v + sum_j a_j * z[src_j].
__global__ __launch_bounds__(256) void prop_rec_kernel(
    const __half* __restrict__ zin,
    const __half* __restrict__ vh,
    const uint4* __restrict__ recs,
    const int* __restrict__ row_ptr,
    __half* __restrict__ zout) {
    int gid = blockIdx.x * 256 + threadIdx.x;
    int node = gid >> 3;
    if (node >= NN) return;
    int l = gid & 7;
    int head = l >> 1;
    const uint4* z4 = (const uint4*)zin;
    float m[8];
    #pragma unroll
    for (int i = 0; i < 8; ++i) m[i] = 0.f;
    int beg = row_ptr[node], end = row_ptr[node + 1];
    int j = beg;
    for (; j + 4 <= end; j += 4) {
        uint4 r0 = recs[j], r1 = recs[j + 1], r2 = recs[j + 2], r3 = recs[j + 3];
        uint4 z0 = z4[(size_t)r0.x * 8 + l];
        uint4 z1 = z4[(size_t)r1.x * 8 + l];
        uint4 z2 = z4[(size_t)r2.x * 8 + l];
        uint4 z3 = z4[(size_t)r3.x * 8 + l];
        float a0 = rec_att(r0, head), a1 = rec_att(r1, head);
        float a2 = rec_att(r2, head), a3 = rec_att(r3, head);
        ACC8(a0, z0); ACC8(a1, z1); ACC8(a2, z2); ACC8(a3, z3);
    }
    for (; j < end; ++j) {
        uint4 r = recs[j];
        uint4 zl = z4[(size_t)r.x * 8 + l];
        float a = rec_att(r, head);
        ACC8(a, zl);
    }
    uint4 vv = ((const uint4*)vh)[(size_t)node * 8 + l];
    float2 v0 = h2f(vv.x), v1 = h2f(vv.y), v2 = h2f(vv.z), v3 = h2f(vv.w);
    uint4 o;
    o.x = f2h2(ALPHA * v0.x + m[0], ALPHA * v0.y + m[1]);
    o.y = f2h2(ALPHA * v1.x + m[2], ALPHA * v1.y + m[3]);
    o.z = f2h2(ALPHA * v2.x + m[4], ALPHA * v2.y + m[5]);
    o.w = f2h2(ALPHA * v3.x + m[6], ALPHA * v3.y + m[7]);
    ((uint4*)zout)[(size_t)node * 8 + l] = o;
}

// Final iteration fused with epilogue: out = x + relu(z_new), fp32 out.
__global__ __launch_bounds__(256) void prop_out_rec_kernel(
    const __half* __restrict__ zin,
    const __half* __restrict__ vh,
    const uint4* __restrict__ recs,
    const int* __restrict__ row_ptr,
    const float* __restrict__ x,
    float* __restrict__ out) {
    int gid = blockIdx.x * 256 + threadIdx.x;
    int node = gid >> 3;
    if (node >= NN) return;
    int l = gid & 7;
    int head = l >> 1;
    const uint4* z4 = (const uint4*)zin;
    float m[8];
    #pragma unroll
    for (int i = 0; i < 8; ++i) m[i] = 0.f;
    int beg = row_ptr[node], end = row_ptr[node + 1];
    int j = beg;
    for (; j + 4 <= end; j += 4) {
        uint4 r0 = recs[j], r1 = recs[j + 1], r2 = recs[j + 2], r3 = recs[j + 3];
        uint4 z0 = z4[(size_t)r0.x * 8 + l];
        uint4 z1 = z4[(size_t)r1.x * 8 + l];
        uint4 z2 = z4[(size_t)r2.x * 8 + l];
        uint4 z3 = z4[(size_t)r3.x * 8 + l];
        float a0 = rec_att(r0, head), a1 = rec_att(r1, head);
        float a2 = rec_att(r2, head), a3 = rec_att(r3, head);
        ACC8(a0, z0); ACC8(a1, z1); ACC8(a2, z2); ACC8(a3, z3);
    }
    for (; j < end; ++j) {
        uint4 r = recs[j];
        uint4 zl = z4[(size_t)r.x * 8 + l];
        float a = rec_att(r, head);
        ACC8(a, zl);
    }
    uint4 vv = ((const uint4*)vh)[(size_t)node * 8 + l];
    float2 v0 = h2f(vv.x), v1 = h2f(vv.y), v2 = h2f(vv.z), v3 = h2f(vv.w);
    float zf[8] = { ALPHA * v0.x + m[0], ALPHA * v0.y + m[1],
                    ALPHA * v1.x + m[2], ALPHA * v1.y + m[3],
                    ALPHA * v2.x + m[4], ALPHA * v2.y + m[5],
                    ALPHA * v3.x + m[6], ALPHA * v3.y + m[7] };
    const float4* x4 = (const float4*)x + (size_t)node * 16 + l * 2;
    float4 xa = x4[0], xb = x4[1];
    float4 oa, ob;
    oa.x = xa.x + fmaxf(zf[0], 0.f); oa.y = xa.y + fmaxf(zf[1], 0.f);
    oa.z = xa.z + fmaxf(zf[2], 0.f); oa.w = xa.w + fmaxf(zf[3], 0.f);
    ob.x = xb.x + fmaxf(zf[4], 0.f); ob.y = xb.y + fmaxf(zf[5], 0.f);
    ob.z = xb.z + fmaxf(zf[6], 0.f); ob.w = xb.w + fmaxf(zf[7], 0.f);
    float4* o4 = (float4*)out + (size_t)node * 16 + l * 2;
    o4[0] = oa; o4[1] = ob;
}

extern "C" void kernel_launch(void* const* d_in, const int* in_sizes, int n_in,
                              void* d_out, int out_size, void* d_ws, size_t ws_size,
                              hipStream_t stream) {
    const float* x         = (const float*)d_in[0];
    const int*   ei        = (const int*)d_in[1];   // [2, NE]: row0=src, row1=dst
    const float* edge_attr = (const float*)d_in[2];
    const float* Wq        = (const float*)d_in[3];
    const float* Wk        = (const float*)d_in[4];
    const float* Wv        = (const float*)d_in[5];
    const float* We        = (const float*)d_in[6];
    float* out = (float*)d_out;

    // ws layout (~147 MB, no aliasing). All segment sizes are 16B-multiples,
    // so recs (uint4) stays 16B-aligned.
    __half* qh = (__half*)d_ws;                        // NN*64
    __half* kh = qh + (size_t)NN * DIM;                // NN*64
    __half* vh = kh + (size_t)NN * DIM;                // NN*64
    unsigned short* u = (unsigned short*)(vh + (size_t)NN * DIM);  // NN*256 bf16
    __half* zha = (__half*)(u + (size_t)NN * 256);     // NN*64
    __half* zhb = zha + (size_t)NN * DIM;              // NN*64
    __half* att_e = zhb + (size_t)NN * DIM;            // NE*4 (edge order, raw exp)
    float* rinv  = (float*)(att_e + (size_t)NE * HEADS); // NN*4
    uint4* recs  = (uint4*)(rinv + (size_t)NN * HEADS);  // NE (16B each)
    int* deg     = (int*)(recs + (size_t)NE);          // NN
    int* bsum    = deg + NN;                           // NBLK
    int* boff    = bsum + NBLK;                        // NBLK
    int* row_ptr = boff + NBLK;                        // NN+1
    int* cursor  = row_ptr + NN + 1;                   // NN
    int* csr_src = cursor + NN;                        // NE
    int* csr_e   = csr_src + NE;                       // NE
    int* csr_dst = csr_e + NE;                         // NE

    hipLaunchKernelGGL(qkv_mfma_kernel, dim3((NN + 63) / 64), dim3(256), 0, stream,
                       x, Wq, Wk, Wv, We, qh, kh, vh, u);
    hipLaunchKernelGGL(init_kernel, dim3((NN + 255) / 256), dim3(256), 0, stream,
                       deg);
    hipLaunchKernelGGL(deg_kernel, dim3((NE + 255) / 256), dim3(256), 0, stream,
                       ei, deg);
    hipLaunchKernelGGL(blocksum_kernel, dim3(NBLK), dim3(256), 0, stream,
                       deg, bsum);
    hipLaunchKernelGGL(bscan_kernel, dim3(1), dim3(512), 0, stream,
                       bsum, boff);
    hipLaunchKernelGGL(rowptr_kernel, dim3(NBLK), dim3(256), 0, stream,
                       deg, boff, row_ptr, cursor);
    hipLaunchKernelGGL(scatter_kernel, dim3((NE + 255) / 256), dim3(256), 0, stream,
                       ei, cursor, csr_src, csr_e, csr_dst);
    hipLaunchKernelGGL(logits_edge_kernel, dim3(NE * HEADS / 256), dim3(256), 0, stream,
                       qh, kh, edge_attr, u, ei, att_e);
    hipLaunchKernelGGL(rinv_kernel, dim3((NN * HEADS + 255) / 256), dim3(256), 0, stream,
                       att_e, csr_e, row_ptr, rinv);
    hipLaunchKernelGGL(recs_kernel, dim3((NE + 255) / 256), dim3(256), 0, stream,
                       att_e, csr_src, csr_e, csr_dst, rinv, recs);

    const __half* zin = vh;
    __half* zout = zha;
    for (int it = 0; it < K_ITERS - 1; ++it) {
        hipLaunchKernelGGL(prop_rec_kernel, dim3((NN * 8 + 255) / 256), dim3(256), 0, stream,
                           zin, vh, recs, row_ptr, zout);
        zin = zout;
        zout = (zout == zha) ? zhb : zha;
    }
    hipLaunchKernelGGL(prop_out_rec_kernel, dim3((NN * 8 + 255) / 256), dim3(256), 0, stream,
                       zin, vh, recs, row_ptr, x, out);
}

// Round 3
// 800.622 us; speedup vs baseline: 1.0584x; 1.0584x over previous
//
#include <hip/hip_runtime.h>
#include <hip/hip_fp16.h>
#include <cstdint>
#include <cstddef>

#define NN 100000
#define NE 800000
#define DIM 64
#define HEADS 4
#define HEAD_DIM 16
#define ALPHA 0.1f
#define K_ITERS 8
#define NBLK 391  // ceil(NN/256)

typedef short bf16x8 __attribute__((ext_vector_type(8)));
typedef float f32x4 __attribute__((ext_vector_type(4)));
typedef float fvec4 __attribute__((ext_vector_type(4)));  // for nontemporal builtin

__device__ __forceinline__ unsigned short f2bf(float f) {
    unsigned int x = __float_as_uint(f);
    unsigned int r = (x + 0x7fffu + ((x >> 16) & 1u)) >> 16;  // RNE
    return (unsigned short)r;
}
__device__ __forceinline__ float bf_lo(unsigned int p) { return __uint_as_float(p << 16); }
__device__ __forceinline__ float bf_hi(unsigned int p) { return __uint_as_float(p & 0xffff0000u); }

__device__ __forceinline__ float2 h2f(unsigned int v) {
    __half2 h = *(__half2*)&v;
    return __half22float2(h);
}
__device__ __forceinline__ unsigned int f2h2(float a, float b) {
    __half2 h = __floats2half2_rn(a, b);
    return *(unsigned int*)&h;
}
__device__ __forceinline__ float dot8h(uint4 a, uint4 b) {
    float2 a0 = h2f(a.x), b0 = h2f(b.x);
    float2 a1 = h2f(a.y), b1 = h2f(b.y);
    float2 a2 = h2f(a.z), b2 = h2f(b.z);
    float2 a3 = h2f(a.w), b3 = h2f(b.w);
    return a0.x * b0.x + a0.y * b0.y + a1.x * b1.x + a1.y * b1.y
         + a2.x * b2.x + a2.y * b2.y + a3.x * b3.x + a3.y * b3.y;
}
// dot of 8 fp32 (two fvec4 chunks) with 8 bf16 packed in a uint4
__device__ __forceinline__ float dot8bf(fvec4 a0, fvec4 a1, uint4 up) {
    return a0.x * bf_lo(up.x) + a0.y * bf_hi(up.x)
         + a0.z * bf_lo(up.y) + a0.w * bf_hi(up.y)
         + a1.x * bf_lo(up.z) + a1.y * bf_hi(up.z)
         + a1.z * bf_lo(up.w) + a1.w * bf_hi(up.w);
}

// NOTE: macro parameter must NOT be named 'z' (or x/y/w) — member tokens
// .x/.y/.z/.w would be substituted too.
#define ACC8(a, V) { float2 t_; \
    t_ = h2f((V).x); m[0] += (a) * t_.x; m[1] += (a) * t_.y; \
    t_ = h2f((V).y); m[2] += (a) * t_.x; m[3] += (a) * t_.y; \
    t_ = h2f((V).z); m[4] += (a) * t_.x; m[5] += (a) * t_.y; \
    t_ = h2f((V).w); m[6] += (a) * t_.x; m[7] += (a) * t_.y; }

// att extractor from packed rec: rec.y holds heads 0,1; rec.z holds heads 2,3.
__device__ __forceinline__ float rec_att(uint4 r, int head) {
    unsigned int pair = (head & 2) ? r.z : r.y;
    float2 f = h2f(pair);
    return (head & 1) ? f.y : f.x;
}

// MFMA qkv+u: block = 64 nodes, 4 waves x 16 rows each. (unchanged)
__global__ __launch_bounds__(256) void qkv_mfma_kernel(
    const float* __restrict__ x,
    const float* __restrict__ Wq, const float* __restrict__ Wk,
    const float* __restrict__ Wv, const float* __restrict__ We,
    __half* __restrict__ qh, __half* __restrict__ kh, __half* __restrict__ vh,
    unsigned short* __restrict__ u)
{
    __shared__ unsigned short sq[64 * 72];
    int tid = threadIdx.x;
    int w = tid >> 6;
    int lane = tid & 63;
    int m16 = lane & 15;
    int quad = lane >> 4;
    int node = blockIdx.x * 64 + w * 16 + m16;
    int nodeC = node < NN ? node : NN - 1;

    bf16x8 afrag[2];
    #pragma unroll
    for (int kk = 0; kk < 2; ++kk) {
        const float* xr = x + (size_t)nodeC * DIM + kk * 32 + quad * 8;
        #pragma unroll
        for (int j = 0; j < 8; ++j) afrag[kk][j] = (short)f2bf(xr[j]);
    }

    const float* Ws[3] = {Wq, Wk, Wv};
    __half* outs[3] = {qh, kh, vh};

    #pragma unroll
    for (int mtx = 0; mtx < 3; ++mtx) {
        const float* W = Ws[mtx];
        #pragma unroll
        for (int n0 = 0; n0 < 64; n0 += 16) {
            int col = n0 + m16;
            f32x4 acc = {0.f, 0.f, 0.f, 0.f};
            #pragma unroll
            for (int kk = 0; kk < 2; ++kk) {
                bf16x8 bfrag;
                #pragma unroll
                for (int j = 0; j < 8; ++j)
                    bfrag[j] = (short)f2bf(W[(kk * 32 + quad * 8 + j) * DIM + col]);
                acc = __builtin_amdgcn_mfma_f32_16x16x32_bf16(afrag[kk], bfrag, acc, 0, 0, 0);
            }
            if (mtx == 0) {
                #pragma unroll
                for (int r = 0; r < 4; ++r) acc[r] *= 0.25f;  // fold 1/sqrt(HEAD_DIM)
            }
            #pragma unroll
            for (int r = 0; r < 4; ++r) {
                int rl = w * 16 + quad * 4 + r;
                int gnode = blockIdx.x * 64 + rl;
                if (mtx == 0) sq[rl * 72 + col] = f2bf(acc[r]);
                if (gnode < NN) outs[mtx][(size_t)gnode * DIM + col] = __float2half(acc[r]);
            }
        }
    }
    __syncthreads();

    #pragma unroll
    for (int h = 0; h < HEADS; ++h) {
        int kk = h >> 1;
        bf16x8 aq;
        const unsigned short* sr = &sq[(w * 16 + m16) * 72 + kk * 32 + quad * 8];
        #pragma unroll
        for (int j = 0; j < 8; ++j) aq[j] = (short)sr[j];
        #pragma unroll
        for (int c0 = 0; c0 < 64; c0 += 16) {
            int c = c0 + m16;
            bf16x8 bfrag;
            #pragma unroll
            for (int j = 0; j < 8; ++j) {
                int k = kk * 32 + quad * 8 + j;
                bfrag[j] = ((k >> 4) == h) ? (short)f2bf(We[c * DIM + k]) : (short)0;
            }
            f32x4 acc = {0.f, 0.f, 0.f, 0.f};
            acc = __builtin_amdgcn_mfma_f32_16x16x32_bf16(aq, bfrag, acc, 0, 0, 0);
            #pragma unroll
            for (int r = 0; r < 4; ++r) {
                int gnode = blockIdx.x * 64 + w * 16 + quad * 4 + r;
                if (gnode < NN) u[(size_t)gnode * 256 + h * 64 + c] = f2bf(acc[r]);
            }
        }
    }
}

__global__ void init_kernel(int* __restrict__ deg) {
    int i = blockIdx.x * 256 + threadIdx.x;
    if (i < NN) deg[i] = 0;
}

__global__ void deg_kernel(const int* __restrict__ ei, int* __restrict__ deg) {
    int e = blockIdx.x * 256 + threadIdx.x;
    if (e >= NE) return;
    atomicAdd(&deg[ei[NE + e]], 1);
}

__global__ void blocksum_kernel(const int* __restrict__ deg, int* __restrict__ bsum) {
    int t = threadIdx.x, b = blockIdx.x;
    int idx = b * 256 + t;
    int v = (idx < NN) ? deg[idx] : 0;
    #pragma unroll
    for (int off = 32; off > 0; off >>= 1) v += __shfl_down(v, off);
    __shared__ int wsum[4];
    if ((t & 63) == 0) wsum[t >> 6] = v;
    __syncthreads();
    if (t == 0) bsum[b] = wsum[0] + wsum[1] + wsum[2] + wsum[3];
}

__global__ void bscan_kernel(const int* __restrict__ bsum, int* __restrict__ boff) {
    __shared__ int s[512];
    int t = threadIdx.x;
    int v = (t < NBLK) ? bsum[t] : 0;
    s[t] = v;
    __syncthreads();
    for (int off = 1; off < 512; off <<= 1) {
        int u = (t >= off) ? s[t - off] : 0;
        __syncthreads();
        s[t] += u;
        __syncthreads();
    }
    if (t < NBLK) boff[t] = s[t] - v;
}

__global__ void rowptr_kernel(const int* __restrict__ deg, const int* __restrict__ boff,
                              int* __restrict__ row_ptr, int* __restrict__ cursor) {
    __shared__ int s[256];
    int t = threadIdx.x, b = blockIdx.x;
    int idx = b * 256 + t;
    int v = (idx < NN) ? deg[idx] : 0;
    s[t] = v;
    __syncthreads();
    for (int off = 1; off < 256; off <<= 1) {
        int u = (t >= off) ? s[t - off] : 0;
        __syncthreads();
        s[t] += u;
        __syncthreads();
    }
    if (idx < NN) {
        int ex = boff[b] + s[t] - v;
        row_ptr[idx] = ex;
        cursor[idx] = ex;
    }
    if (idx == 0) row_ptr[NN] = NE;
}

__global__ void scatter_kernel(const int* __restrict__ ei,
                               int* __restrict__ cursor,
                               int* __restrict__ csr_src,
                               int* __restrict__ csr_e,
                               int* __restrict__ csr_dst) {
    int e = blockIdx.x * 256 + threadIdx.x;
    if (e >= NE) return;
    int src = ei[e], dst = ei[NE + e];
    int pos = atomicAdd(&cursor[dst], 1);
    csr_src[pos] = src;
    csr_e[pos] = e;
    csr_dst[pos] = dst;
}

// CSR-order logits, ONE thread per CSR slot, all 4 heads in-thread.
// dst-side rows (u 512B, qh 128B) are consecutive across the wave -> cached;
// attr rows (256B) random but fully consumed (no overfetch); no atomics.
// att[j] = uint2 of 4 fp16 raw exps (CSR-slot order, coalesced 8B writes).
__global__ __launch_bounds__(256) void logits_csr2_kernel(
    const __half* __restrict__ qh,
    const __half* __restrict__ kh,
    const float* __restrict__ edge_attr,
    const unsigned short* __restrict__ u,
    const int* __restrict__ csr_src,
    const int* __restrict__ csr_e,
    const int* __restrict__ csr_dst,
    uint2* __restrict__ att) {
    int j = blockIdx.x * 256 + threadIdx.x;
    if (j >= NE) return;
    int src = csr_src[j], dst = csr_dst[j], e = csr_e[j];
    const fvec4* attr4 = (const fvec4*)edge_attr + (size_t)e * 16;
    const uint4* urow = (const uint4*)u + (size_t)dst * 32;
    float au0 = 0.f, au1 = 0.f, au2 = 0.f, au3 = 0.f;
    #pragma unroll
    for (int i = 0; i < 8; ++i) {
        fvec4 a0 = __builtin_nontemporal_load(attr4 + 2 * i);
        fvec4 a1 = __builtin_nontemporal_load(attr4 + 2 * i + 1);
        au0 += dot8bf(a0, a1, urow[0 * 8 + i]);
        au1 += dot8bf(a0, a1, urow[1 * 8 + i]);
        au2 += dot8bf(a0, a1, urow[2 * 8 + i]);
        au3 += dot8bf(a0, a1, urow[3 * 8 + i]);
    }
    const uint4* qq = (const uint4*)qh + (size_t)dst * 8;
    const uint4* kk = (const uint4*)kh + (size_t)src * 8;
    float qk0 = dot8h(qq[0], kk[0]) + dot8h(qq[1], kk[1]);
    float qk1 = dot8h(qq[2], kk[2]) + dot8h(qq[3], kk[3]);
    float qk2 = dot8h(qq[4], kk[4]) + dot8h(qq[5], kk[5]);
    float qk3 = dot8h(qq[6], kk[6]) + dot8h(qq[7], kk[7]);
    float e0 = __expf(qk0 + au0);
    float e1 = __expf(qk1 + au1);
    float e2 = __expf(qk2 + au2);
    float e3 = __expf(qk3 + au3);
    uint2 o;
    o.x = f2h2(e0, e1);
    o.y = f2h2(e2, e3);
    att[j] = o;
}

// Fused per-node pass: row-sum raw exps (4 heads) -> rinv, then pack recs
// {src, fp16 att*rinv}. All att/csr_src reads sequential (CSR order).
__global__ void recs_fused_kernel(const uint2* __restrict__ att,
                                  const int* __restrict__ csr_src,
                                  const int* __restrict__ row_ptr,
                                  uint4* __restrict__ recs) {
    int n = blockIdx.x * 256 + threadIdx.x;
    if (n >= NN) return;
    int beg = row_ptr[n], end = row_ptr[n + 1];
    float s0 = 1e-16f, s1 = 1e-16f, s2 = 1e-16f, s3 = 1e-16f;
    for (int j = beg; j < end; ++j) {
        uint2 ap = att[j];
        float2 p01 = h2f(ap.x), p23 = h2f(ap.y);
        s0 += p01.x; s1 += p01.y; s2 += p23.x; s3 += p23.y;
    }
    float r0 = 0.9f / s0, r1 = 0.9f / s1, r2 = 0.9f / s2, r3 = 0.9f / s3;
    for (int j = beg; j < end; ++j) {
        uint2 ap = att[j];
        float2 p01 = h2f(ap.x), p23 = h2f(ap.y);
        uint4 rec;
        rec.x = (unsigned int)csr_src[j];
        rec.y = f2h2(p01.x * r0, p01.y * r1);
        rec.z = f2h2(p23.x * r2, p23.y * r3);
        rec.w = 0u;
        recs[j] = rec;
    }
}

// Propagation: 8 lanes/node, 8 dims/lane. Weights pre-normalized (x0.9/denom),
// so z_out = alpha*v + sum_j a_j * z[src_j]. Unroll-8 for deeper MLP on the
// dependent recs->z chain.
__global__ __launch_bounds__(256) void prop_rec_kernel(
    const __half* __restrict__ zin,
    const __half* __restrict__ vh,
    const uint4* __restrict__ recs,
    const int* __restrict__ row_ptr,
    __half* __restrict__ zout) {
    int gid = blockIdx.x * 256 + threadIdx.x;
    int node = gid >> 3;
    if (node >= NN) return;
    int l = gid & 7;
    int head = l >> 1;
    const uint4* z4 = (const uint4*)zin;
    float m[8];
    #pragma unroll
    for (int i = 0; i < 8; ++i) m[i] = 0.f;
    int beg = row_ptr[node], end = row_ptr[node + 1];
    int j = beg;
    for (; j + 8 <= end; j += 8) {
        uint4 r[8], zz[8];
        #pragma unroll
        for (int t = 0; t < 8; ++t) r[t] = recs[j + t];
        #pragma unroll
        for (int t = 0; t < 8; ++t) zz[t] = z4[(size_t)r[t].x * 8 + l];
        #pragma unroll
        for (int t = 0; t < 8; ++t) { float a = rec_att(r[t], head); ACC8(a, zz[t]); }
    }
    for (; j + 4 <= end; j += 4) {
        uint4 r0 = recs[j], r1 = recs[j + 1], r2 = recs[j + 2], r3 = recs[j + 3];
        uint4 z0 = z4[(size_t)r0.x * 8 + l];
        uint4 z1 = z4[(size_t)r1.x * 8 + l];
        uint4 z2 = z4[(size_t)r2.x * 8 + l];
        uint4 z3 = z4[(size_t)r3.x * 8 + l];
        float a0 = rec_att(r0, head), a1 = rec_att(r1, head);
        float a2 = rec_att(r2, head), a3 = rec_att(r3, head);
        ACC8(a0, z0); ACC8(a1, z1); ACC8(a2, z2); ACC8(a3, z3);
    }
    for (; j < end; ++j) {
        uint4 r = recs[j];
        uint4 zl = z4[(size_t)r.x * 8 + l];
        float a = rec_att(r, head);
        ACC8(a, zl);
    }
    uint4 vv = ((const uint4*)vh)[(size_t)node * 8 + l];
    float2 v0 = h2f(vv.x), v1 = h2f(vv.y), v2 = h2f(vv.z), v3 = h2f(vv.w);
    uint4 o;
    o.x = f2h2(ALPHA * v0.x + m[0], ALPHA * v0.y + m[1]);
    o.y = f2h2(ALPHA * v1.x + m[2], ALPHA * v1.y + m[3]);
    o.z = f2h2(ALPHA * v2.x + m[4], ALPHA * v2.y + m[5]);
    o.w = f2h2(ALPHA * v3.x + m[6], ALPHA * v3.y + m[7]);
    ((uint4*)zout)[(size_t)node * 8 + l] = o;
}

// Final iteration fused with epilogue: out = x + relu(z_new), fp32 out.
__global__ __launch_bounds__(256) void prop_out_rec_kernel(
    const __half* __restrict__ zin,
    const __half* __restrict__ vh,
    const uint4* __restrict__ recs,
    const int* __restrict__ row_ptr,
    const float* __restrict__ x,
    float* __restrict__ out) {
    int gid = blockIdx.x * 256 + threadIdx.x;
    int node = gid >> 3;
    if (node >= NN) return;
    int l = gid & 7;
    int head = l >> 1;
    const uint4* z4 = (const uint4*)zin;
    float m[8];
    #pragma unroll
    for (int i = 0; i < 8; ++i) m[i] = 0.f;
    int beg = row_ptr[node], end = row_ptr[node + 1];
    int j = beg;
    for (; j + 8 <= end; j += 8) {
        uint4 r[8], zz[8];
        #pragma unroll
        for (int t = 0; t < 8; ++t) r[t] = recs[j + t];
        #pragma unroll
        for (int t = 0; t < 8; ++t) zz[t] = z4[(size_t)r[t].x * 8 + l];
        #pragma unroll
        for (int t = 0; t < 8; ++t) { float a = rec_att(r[t], head); ACC8(a, zz[t]); }
    }
    for (; j + 4 <= end; j += 4) {
        uint4 r0 = recs[j], r1 = recs[j + 1], r2 = recs[j + 2], r3 = recs[j + 3];
        uint4 z0 = z4[(size_t)r0.x * 8 + l];
        uint4 z1 = z4[(size_t)r1.x * 8 + l];
        uint4 z2 = z4[(size_t)r2.x * 8 + l];
        uint4 z3 = z4[(size_t)r3.x * 8 + l];
        float a0 = rec_att(r0, head), a1 = rec_att(r1, head);
        float a2 = rec_att(r2, head), a3 = rec_att(r3, head);
        ACC8(a0, z0); ACC8(a1, z1); ACC8(a2, z2); ACC8(a3, z3);
    }
    for (; j < end; ++j) {
        uint4 r = recs[j];
        uint4 zl = z4[(size_t)r.x * 8 + l];
        float a = rec_att(r, head);
        ACC8(a, zl);
    }
    uint4 vv = ((const uint4*)vh)[(size_t)node * 8 + l];
    float2 v0 = h2f(vv.x), v1 = h2f(vv.y), v2 = h2f(vv.z), v3 = h2f(vv.w);
    float zf[8] = { ALPHA * v0.x + m[0], ALPHA * v0.y + m[1],
                    ALPHA * v1.x + m[2], ALPHA * v1.y + m[3],
                    ALPHA * v2.x + m[4], ALPHA * v2.y + m[5],
                    ALPHA * v3.x + m[6], ALPHA * v3.y + m[7] };
    const float4* x4 = (const float4*)x + (size_t)node * 16 + l * 2;
    float4 xa = x4[0], xb = x4[1];
    float4 oa, ob;
    oa.x = xa.x + fmaxf(zf[0], 0.f); oa.y = xa.y + fmaxf(zf[1], 0.f);
    oa.z = xa.z + fmaxf(zf[2], 0.f); oa.w = xa.w + fmaxf(zf[3], 0.f);
    ob.x = xb.x + fmaxf(zf[4], 0.f); ob.y = xb.y + fmaxf(zf[5], 0.f);
    ob.z = xb.z + fmaxf(zf[6], 0.f); ob.w = xb.w + fmaxf(zf[7], 0.f);
    float4* o4 = (float4*)out + (size_t)node * 16 + l * 2;
    o4[0] = oa; o4[1] = ob;
}

extern "C" void kernel_launch(void* const* d_in, const int* in_sizes, int n_in,
                              void* d_out, int out_size, void* d_ws, size_t ws_size,
                              hipStream_t stream) {
    const float* x         = (const float*)d_in[0];
    const int*   ei        = (const int*)d_in[1];   // [2, NE]: row0=src, row1=dst
    const float* edge_attr = (const float*)d_in[2];
    const float* Wq        = (const float*)d_in[3];
    const float* Wk        = (const float*)d_in[4];
    const float* Wv        = (const float*)d_in[5];
    const float* We        = (const float*)d_in[6];
    float* out = (float*)d_out;

    // ws layout (~145 MB, no aliasing). All segment sizes are 16B-multiples,
    // so recs (uint4) stays 16B-aligned.
    __half* qh = (__half*)d_ws;                        // NN*64
    __half* kh = qh + (size_t)NN * DIM;                // NN*64
    __half* vh = kh + (size_t)NN * DIM;                // NN*64
    unsigned short* u = (unsigned short*)(vh + (size_t)NN * DIM);  // NN*256 bf16
    __half* zha = (__half*)(u + (size_t)NN * 256);     // NN*64
    __half* zhb = zha + (size_t)NN * DIM;              // NN*64
    uint2* att   = (uint2*)(zhb + (size_t)NN * DIM);   // NE (8B: 4 fp16, CSR order)
    uint4* recs  = (uint4*)(att + (size_t)NE);         // NE (16B each)
    int* deg     = (int*)(recs + (size_t)NE);          // NN
    int* bsum    = deg + NN;                           // NBLK
    int* boff    = bsum + NBLK;                        // NBLK
    int* row_ptr = boff + NBLK;                        // NN+1
    int* cursor  = row_ptr + NN + 1;                   // NN
    int* csr_src = cursor + NN;                        // NE
    int* csr_e   = csr_src + NE;                       // NE
    int* csr_dst = csr_e + NE;                         // NE

    hipLaunchKernelGGL(qkv_mfma_kernel, dim3((NN + 63) / 64), dim3(256), 0, stream,
                       x, Wq, Wk, Wv, We, qh, kh, vh, u);
    hipLaunchKernelGGL(init_kernel, dim3((NN + 255) / 256), dim3(256), 0, stream,
                       deg);
    hipLaunchKernelGGL(deg_kernel, dim3((NE + 255) / 256), dim3(256), 0, stream,
                       ei, deg);
    hipLaunchKernelGGL(blocksum_kernel, dim3(NBLK), dim3(256), 0, stream,
                       deg, bsum);
    hipLaunchKernelGGL(bscan_kernel, dim3(1), dim3(512), 0, stream,
                       bsum, boff);
    hipLaunchKernelGGL(rowptr_kernel, dim3(NBLK), dim3(256), 0, stream,
                       deg, boff, row_ptr, cursor);
    hipLaunchKernelGGL(scatter_kernel, dim3((NE + 255) / 256), dim3(256), 0, stream,
                       ei, cursor, csr_src, csr_e, csr_dst);
    hipLaunchKernelGGL(logits_csr2_kernel, dim3((NE + 255) / 256), dim3(256), 0, stream,
                       qh, kh, edge_attr, u, csr_src, csr_e, csr_dst, att);
    hipLaunchKernelGGL(recs_fused_kernel, dim3((NN + 255) / 256), dim3(256), 0, stream,
                       att, csr_src, row_ptr, recs);

    const __half* zin = vh;
    __half* zout = zha;
    for (int it = 0; it < K_ITERS - 1; ++it) {
        hipLaunchKernelGGL(prop_rec_kernel, dim3((NN * 8 + 255) / 256), dim3(256), 0, stream,
                           zin, vh, recs, row_ptr, zout);
        zin = zout;
        zout = (zout == zha) ? zhb : zha;
    }
    hipLaunchKernelGGL(prop_out_rec_kernel, dim3((NN * 8 + 255) / 256), dim3(256), 0, stream,
                       zin, vh, recs, row_ptr, x, out);
}